// Round 9
// baseline (198.913 us; speedup 1.0000x reference)
//
#include <hip/hip_runtime.h>

// Inputs/outputs fp32; internal compute bf16 MFMA (bf16-grade comparison).
// ws layout (64 MB):
//   [0,16M)   Yp    fp32 [B,S,D]
//   [16M,24M) Xb    bf16 [B*S, D]
//   [24M,30M) Wcat  bf16 [3072,1024]
//   [30M,32M) Wob   bf16 [1024,1024]
//   [32M,40M) Qb    bf16 [B,H,S,DK] (post-PE, pre-scaled by 0.125/ln2)
//   [40M,48M) Kraw  bf16 [B,H,S,DK] -> reused as Ab bf16 [B,S,D] after ema_pe
//   [48M,56M) Kp    bf16 packed K-frag order [bh][kt16][c][lane][j8]
//   [56M,64M) Vp    bf16 packed V^T-frag order [bh][kb64][t*4+dn][lane][j4]

#define LB __launch_bounds__(256)
// r6/r8/r15: NO min-waves hint / extra register footprint on attn.
// r10: NO loop-carried MFMA accumulator chains.
// R16: attn = 64-row blocks + LDS K/V staging; uniform 33 steps/block.
// R17/R18/R19 (counter-verified): epilogue register pressure is a first-class
// occupancy knob (76 vs 120 VGPR = 41.6 vs 59us); serial cores live off TLP.
// R20 (94.5us): 8-phase 256^2 starves here -- needs grid>=CUs and long K.
// R21 (57us): 64x128 qkv tiles regress -- serial core bound by staging-issue
// rate per MFMA; 128^2 tile is the local optimum for qkv.
// R22: attn 3-buf depth-2 counted vmcnt(4) (T4) -- WORKED (~2x, attn ~20us).
// R23: T1 XCD-chunked block swizzle on both GEMMs; total 190.8 (best).
// R24: same T4 pipeline ported to gemm_qkv. KEY INSIGHT: R2's "dbuf neutral"
// verdict used __syncthreads, whose implicit vmcnt(0) DRAINS the prefetch --
// counted-vmcnt + raw s_barrier was never actually tested on the GEMM core.
// 3 LDS buf-pairs (48KB, still 3 blocks/CU which grid=768 caps anyway); per
// step: stage(kt+2) -> ds_read+MFMA buf[kt%3] -> vmcnt(4) -> s_barrier.
// Ledger (per wave, 4 GLDS/step): vmcnt(4) at step k end => stage(k+1)
// complete; end-of-step-k barrier => all reads of buf[k%3] done before step
// k+1 overwrites it (k+3===k mod 3); tail drains to 0.

typedef unsigned short u16;
typedef unsigned int u32;
typedef __attribute__((ext_vector_type(2))) unsigned int u32x2;
typedef __attribute__((ext_vector_type(4))) unsigned short us4;
typedef __attribute__((ext_vector_type(8))) unsigned short us8;
typedef __attribute__((ext_vector_type(8))) __bf16 bf8;
typedef __attribute__((ext_vector_type(4))) float f4;
typedef __attribute__((ext_vector_type(4))) short s4;

// softmax scale folded into Q: exp(s/8) = exp2(s * 0.125/ln2)
#define QSCALE 0.18033688011112042f

#if __has_builtin(__builtin_amdgcn_exp2f)
#define EXP2 __builtin_amdgcn_exp2f   // raw v_exp_f32 (r14-validated: args never denormal)
#else
#define EXP2 exp2f
#endif

static __device__ __forceinline__ float bf2f(u16 h) {
  union { unsigned int u; float f; } c; c.u = ((unsigned int)h) << 16; return c.f;
}
static __device__ __forceinline__ u16 f2bf(float f) {
  union { float f; unsigned int u; } c; c.f = f;
  unsigned int u = c.u + 0x7FFFu + ((c.u >> 16) & 1u);
  return (u16)(u >> 16);
}
// pack 4 fp32 -> 4 bf16 (RNE); packed HW cvt when available
#if __has_builtin(__builtin_amdgcn_cvt_pk_bf16_f32)
typedef __attribute__((ext_vector_type(2))) __bf16 bf2v;
static __device__ __forceinline__ us4 pk_bf16x4(f4 v) {
  bf2v lo = __builtin_amdgcn_cvt_pk_bf16_f32(v[0], v[1]);
  bf2v hi = __builtin_amdgcn_cvt_pk_bf16_f32(v[2], v[3]);
  u32x2 r = {__builtin_bit_cast(u32, lo), __builtin_bit_cast(u32, hi)};
  return __builtin_bit_cast(us4, r);
}
#else
static __device__ __forceinline__ us4 pk_bf16x4(f4 v) {
  return us4{f2bf(v[0]), f2bf(v[1]), f2bf(v[2]), f2bf(v[3])};
}
#endif
static __device__ __forceinline__ float pe_val(int s, int dk) {
  float fr = __expf((float)(dk & ~1) * (-9.210340371976184f / 64.0f));
  float ang = (float)s * fr;
  return (dk & 1) ? __cosf(ang) : __sinf(ang);
}

// 16x16x16 bf16 MFMA, hedged across builtin generations (verified r5).
#if __has_builtin(__builtin_amdgcn_mfma_f32_16x16x16bf16_1k)
static __device__ __forceinline__ f4 mfma16(us4 a, us4 b, f4 c) {
  return __builtin_amdgcn_mfma_f32_16x16x16bf16_1k(
      __builtin_bit_cast(s4, a), __builtin_bit_cast(s4, b), c, 0, 0, 0);
}
#elif __has_builtin(__builtin_amdgcn_mfma_f32_16x16x16_bf16)
typedef __attribute__((ext_vector_type(4))) __bf16 bf4;
static __device__ __forceinline__ f4 mfma16(us4 a, us4 b, f4 c) {
  return __builtin_amdgcn_mfma_f32_16x16x16_bf16(
      __builtin_bit_cast(bf4, a), __builtin_bit_cast(bf4, b), c, 0, 0, 0);
}
#else
static __device__ __forceinline__ f4 mfma16(us4 a, us4 b, f4 c) {
  asm volatile("v_mfma_f32_16x16x16_bf16 %0, %1, %2, %0" : "+v"(c) : "v"(a), "v"(b));
  return c;
}
#endif

#define GLDS(gp, lp) __builtin_amdgcn_global_load_lds( \
    (const __attribute__((address_space(1))) void*)(gp), \
    (__attribute__((address_space(3))) void*)(lp), 16, 0, 0)

// ---------------- fp32 -> bf16 conversion pre-pass ----------------
__global__ LB void cvt_kernel(const float* __restrict__ X, const float* __restrict__ Wq,
                              const float* __restrict__ Wk, const float* __restrict__ Wv,
                              const float* __restrict__ Wo, u16* __restrict__ Xb,
                              u16* __restrict__ Wcat, u16* __restrict__ Wob) {
  const unsigned t = blockIdx.x * 256 + threadIdx.x;
  const float* src; u16* dst; size_t off;
  if (t < (512u << 10))      { src = X;  dst = Xb;                off = t; }
  else if (t < (640u << 10)) { src = Wq; dst = Wcat;              off = t - (512u << 10); }
  else if (t < (768u << 10)) { src = Wk; dst = Wcat + (1u << 20); off = t - (640u << 10); }
  else if (t < (896u << 10)) { src = Wv; dst = Wcat + (2u << 20); off = t - (768u << 10); }
  else                       { src = Wo; dst = Wob;               off = t - (896u << 10); }
  off *= 8;
  f4 a = *(const f4*)(src + off);
  f4 b = *(const f4*)(src + off + 4);
  us8 o = {f2bf(a[0]), f2bf(a[1]), f2bf(a[2]), f2bf(a[3]),
           f2bf(b[0]), f2bf(b[1]), f2bf(b[2]), f2bf(b[3])};
  *(us8*)(dst + off) = o;
}

// ---------------- QKV projection (fused N=3072) ----------------
// R19 frozen 128^2 tile/epilogue + R24 counted-vmcnt 3-buffer pipeline (T4)
// + R23 T1 XCD swizzle.
__global__ LB void gemm_qkv(const u16* __restrict__ Xb, const u16* __restrict__ Wcat,
                            u16* __restrict__ Qb, u16* __restrict__ Kraw,
                            u16* __restrict__ Vp) {
  __shared__ u16 Als[3][128 * 32];
  __shared__ u16 Bls[3][128 * 32];
  const int tid = threadIdx.x;
  // T1: 768 blocks, 8 XCDs, 96/chunk (bijective since 768%8==0).
  const int wb = (blockIdx.x & 7) * 96 + (blockIdx.x >> 3);
  const int bx = wb % 24, by = wb / 24;
  const int m0 = by * 128, n0 = bx * 128;
  const int w = tid >> 6, lane = tid & 63;
  const int l16 = lane & 15, quad = lane >> 4;
  const int wm = w & 1, wn = w >> 1;

  f4 acc[4][4];
#pragma unroll
  for (int a = 0; a < 4; a++)
#pragma unroll
    for (int b = 0; b < 4; b++) acc[a][b] = f4{0.f, 0.f, 0.f, 0.f};

  // 4 GLDS per thread per step; wave-uniform LDS dest (R19-proven pattern).
#define STAGE_QKV(KK, BUF) do {                                              \
    _Pragma("unroll") for (int it_ = 0; it_ < 2; it_++) {                    \
      int cb_ = (w * 2 + it_) * 64;                                          \
      int c_ = cb_ + lane;                                                   \
      int row_ = c_ >> 2, kc_ = c_ & 3;                                      \
      GLDS(Xb   + (size_t)(m0 + row_) * 1024 + (KK) + kc_ * 8, &Als[BUF][cb_ * 8]); \
      GLDS(Wcat + (size_t)(n0 + row_) * 1024 + (KK) + kc_ * 8, &Bls[BUF][cb_ * 8]); \
    } } while (0)

  // prologue: buf0 + buf1 in flight; vmcnt(4) => buf0 complete.
  STAGE_QKV(0, 0);
  STAGE_QKV(32, 1);
  asm volatile("s_waitcnt vmcnt(4)" ::: "memory");
  __builtin_amdgcn_s_barrier();

  for (int kt = 0; kt < 32; kt++) {
    const int cur = kt % 3;
    if (kt + 2 < 32) STAGE_QKV((kt + 2) * 32, (kt + 2) % 3);
    bf8 af[4], bfr[4];
#pragma unroll
    for (int mt = 0; mt < 4; mt++)
      af[mt] = __builtin_bit_cast(bf8, *(const us8*)(&Als[cur][(wm * 64 + mt * 16 + l16) * 32 + quad * 8]));
#pragma unroll
    for (int nt = 0; nt < 4; nt++)
      bfr[nt] = __builtin_bit_cast(bf8, *(const us8*)(&Bls[cur][(wn * 64 + nt * 16 + l16) * 32 + quad * 8]));
#pragma unroll
    for (int mt = 0; mt < 4; mt++)
#pragma unroll
      for (int nt = 0; nt < 4; nt++)
        acc[mt][nt] = __builtin_amdgcn_mfma_f32_16x16x32_bf16(af[mt], bfr[nt], acc[mt][nt], 0, 0, 0);
    if (kt + 1 < 32) {
      // counted drain (T4): buf[kt+1] complete; only stage(kt+2)'s 4 loads
      // may remain in flight. Tail (nothing staged): full drain.
      if (kt + 2 < 32) { asm volatile("s_waitcnt vmcnt(4)" ::: "memory"); }
      else             { asm volatile("s_waitcnt vmcnt(0)" ::: "memory"); }
      __builtin_amdgcn_s_barrier();  // readers of buf[cur] done before step kt+1 overwrites it
    }
  }
#undef STAGE_QKV

  // epilogue: R19 scalar-store form FROZEN (low register pressure).
  const int z = bx >> 3;  // 0:Q 1:K 2:V
#pragma unroll
  for (int mt = 0; mt < 4; mt++)
#pragma unroll
    for (int nt = 0; nt < 4; nt++)
#pragma unroll
      for (int r = 0; r < 4; r++) {
        int m = m0 + wm * 64 + mt * 16 + quad * 4 + r;
        int nn = (n0 + wn * 64 + nt * 16 + l16) & 1023;
        float v = acc[mt][nt][r];
        int b = m >> 11, s = m & 2047, h = nn >> 6, dk = nn & 63;
        size_t bhoff = (size_t)(b * 16 + h) * (2048 * 64);
        if (z == 0) {
          // pre-scale Q: scores exit QK^T already in exp2 domain
          Qb[bhoff + (size_t)s * 64 + dk] = f2bf((v + pe_val(s, dk)) * QSCALE);
        } else if (z == 1) {
          Kraw[bhoff + (size_t)s * 64 + dk] = f2bf(v);
        } else {
          // packed V^T-frag order: [kb64][(t*4+dn)][Q*16+l16 (=lane)][j]
          int kb = s >> 6, sl = s & 63;
          int t = sl >> 4, Qq = (sl >> 2) & 3, jj = sl & 3;
          int dn = dk >> 4, lv = dk & 15;
          Vp[bhoff + (size_t)kb * 4096 + ((t * 4 + dn) * 64 + Qq * 16 + lv) * 4 + jj] = f2bf(v);
        }
      }
}

// ---------------- EMA smear + PE on K; writes packed K-frag order ----------------
__global__ LB void ema_pe(const u16* __restrict__ Kraw, const float* __restrict__ alpha,
                          u16* __restrict__ Kp) {
  int idx = blockIdx.x * 256 + threadIdx.x;
  int b8  = idx & 7;
  int s   = (idx >> 3) & 2047;
  int bh  = idx >> 14;
  int dk8 = b8 * 8;
  size_t base = ((size_t)bh * 2048 + s) * 64 + dk8;
  us8 kc = *(const us8*)(Kraw + base);
  float kv[8];
#pragma unroll
  for (int j = 0; j < 8; j++) kv[j] = bf2f(kc[j]);
  if (s > 0) {
    us8 kp = *(const us8*)(Kraw + base - 64);
    float aa = alpha[(bh & 15) * 2047 + s - 1];
    float a = 1.0f / (1.0f + __expf(-aa));
#pragma unroll
    for (int j = 0; j < 8; j++) kv[j] = kv[j] * a + bf2f(kp[j]) * (1.0f - a);
  }
  us8 o;
#pragma unroll
  for (int j = 0; j < 8; j++) o[j] = f2bf(kv[j] + pe_val(s, dk8 + j));
  int kt16 = s >> 4, c = b8 >> 2, quad = b8 & 3, l16s = s & 15;
  size_t off = (size_t)bh * (2048 * 64) + (size_t)kt16 * 1024 + (c * 64 + quad * 16 + l16s) * 8;
  *(us8*)(Kp + off) = o;
}

// ---------------- causal attention: 64-row blocks, 3-buf counted-vmcnt K/V ----------------
// Block = 4 waves x 16 q-rows = 64 q-rows sharing one staged K/V stream.
// Two sequential q-groups per block (31-p heavy, then p light) -> 33 steps uniform.
// p = exp2(s) with Q pre-scaled (uniform factor cancels in O = sum(pv)/sum(p)).
template<bool MASK>
static __device__ __forceinline__ void attn_step_lds(
    const u16* kbase, const u16* vbase,
    const bf8* qf, f4* acc, float& lsum, int lane, int quad, int qrel0) {
  f4 sc[4];
#pragma unroll
  for (int t = 0; t < 4; t++) sc[t] = f4{0.f, 0.f, 0.f, 0.f};
#pragma unroll
  for (int t = 0; t < 4; t++)
#pragma unroll
    for (int c = 0; c < 2; c++) {
      bf8 kf = __builtin_bit_cast(bf8, *(const us8*)(kbase + (t * 2 + c) * 512 + lane * 8));
      sc[t] = __builtin_amdgcn_mfma_f32_16x16x32_bf16(kf, qf[c], sc[t], 0, 0, 0);
    }
  us4 pf[4];
#pragma unroll
  for (int t = 0; t < 4; t++) {
    f4 pv;
#pragma unroll
    for (int r = 0; r < 4; r++) {
      float s = sc[t][r];
      if (MASK && (t * 16 + quad * 4 + r > qrel0)) s = -1e30f;
      float p = EXP2(s);          // raw v_exp_f32
      lsum += p;
      pv[r] = p;
    }
    pf[t] = pk_bf16x4(pv);
  }
#pragma unroll
  for (int t = 0; t < 4; t++)
#pragma unroll
    for (int dn = 0; dn < 4; dn++) {
      us4 vf = *(const us4*)(vbase + ((t * 4 + dn) * 64 + lane) * 4);
      acc[dn] = mfma16(vf, pf[t], acc[dn]);
    }
}

__global__ LB void attn_kernel(const u16* __restrict__ Qb, const u16* __restrict__ Kp,
                               const u16* __restrict__ Vp, u16* __restrict__ Ab) {
  __shared__ u16 Kls[3][4096];   // 3-buffer 64-key K tiles (packed frag order)
  __shared__ u16 Vls[3][4096];   // 3-buffer 64-key V^T tiles
  const int tid = threadIdx.x, w = tid >> 6, lane = tid & 63;
  const int l16 = lane & 15, quad = lane >> 4;
  const int idx = blockIdx.x;
  const int bh = idx & 31;        // XCD locality: each XCD's blocks touch only 4 heads
  const int p  = idx >> 5;        // pair index 0..15
  const size_t bhoff = (size_t)bh * (2048 * 64);
  const u16* Kt = Kp + bhoff;
  const u16* Vt = Vp + bhoff;
  const int b = bh >> 4, h = bh & 15;

  for (int ph = 0; ph < 2; ph++) {
    const int g = ph ? p : 31 - p;   // heavy group first, then light: T sums to 33
    const int T = g + 1;             // number of 64-key steps (last one masked)
    const int qw = g * 64 + w * 16;  // this wave's 16 q-rows

    bf8 qf[2];
#pragma unroll
    for (int c = 0; c < 2; c++)
      qf[c] = __builtin_bit_cast(bf8, *(const us8*)(Qb + bhoff + (size_t)(qw + l16) * 64 + c * 32 + quad * 8));

    f4 acc[4];
#pragma unroll
    for (int dn = 0; dn < 4; dn++) acc[dn] = f4{0.f, 0.f, 0.f, 0.f};
    float lsum = 0.f;

    // inter-phase barrier: all waves done READING previous phase's buffers
    // before anyone overwrites them (phase-1 instance is harmless/uniform).
    __builtin_amdgcn_s_barrier();

    // prologue: stage kb=0 (and kb=1 if present); counted drain leaves kb=1's
    // 4 loads in flight -- buf0 is complete, buf1 completes under step 0.
    {
      const u16* kg = Kt + w * 1024;
      const u16* vg = Vt + w * 1024;
      GLDS(kg + lane * 8,       &Kls[0][w * 1024]);
      GLDS(kg + 512 + lane * 8, &Kls[0][w * 1024 + 512]);
      GLDS(vg + lane * 8,       &Vls[0][w * 1024]);
      GLDS(vg + 512 + lane * 8, &Vls[0][w * 1024 + 512]);
    }
    if (T > 1) {
      const u16* kg = Kt + 4096 + w * 1024;
      const u16* vg = Vt + 4096 + w * 1024;
      GLDS(kg + lane * 8,       &Kls[1][w * 1024]);
      GLDS(kg + 512 + lane * 8, &Kls[1][w * 1024 + 512]);
      GLDS(vg + lane * 8,       &Vls[1][w * 1024]);
      GLDS(vg + 512 + lane * 8, &Vls[1][w * 1024 + 512]);
      asm volatile("s_waitcnt vmcnt(4)" ::: "memory");
    } else {
      asm volatile("s_waitcnt vmcnt(0)" ::: "memory");
    }
    __builtin_amdgcn_s_barrier();

    int cur = 0;
    for (int kb = 0; kb < T; kb++) {
      if (kb + 2 < T) {   // stage 2 steps ahead into the buffer freed last step
        int b2 = cur + 2; if (b2 >= 3) b2 -= 3;
        const u16* kg = Kt + (size_t)(kb + 2) * 4096 + w * 1024;
        const u16* vg = Vt + (size_t)(kb + 2) * 4096 + w * 1024;
        u16* kl = &Kls[b2][w * 1024];
        u16* vl = &Vls[b2][w * 1024];
        GLDS(kg + lane * 8, kl);
        GLDS(kg + 512 + lane * 8, kl + 512);
        GLDS(vg + lane * 8, vl);
        GLDS(vg + 512 + lane * 8, vl + 512);
      }
      if (kb == T - 1)
        attn_step_lds<true>(&Kls[cur][0], &Vls[cur][0], qf, acc, lsum, lane, quad, w * 16 + l16);
      else
        attn_step_lds<false>(&Kls[cur][0], &Vls[cur][0], qf, acc, lsum, lane, quad, 0);
      if (kb + 1 < T) {
        // counted drain (T4): buf[kb+1] complete; only the stage(kb+2) loads
        // (newest 4) may remain in flight. Tail (nothing staged): full drain.
        if (kb + 2 < T) { asm volatile("s_waitcnt vmcnt(4)" ::: "memory"); }
        else           { asm volatile("s_waitcnt vmcnt(0)" ::: "memory"); }
        __builtin_amdgcn_s_barrier();   // readers of buf[cur] done; buf[cur] may be re-staged next step
      }
      cur = (cur == 2) ? 0 : cur + 1;
    }

    // epilogue: per-wave softmax denominator (reduce over quads) + store
    lsum += __shfl_xor(lsum, 16, 64);
    lsum += __shfl_xor(lsum, 32, 64);
    float rinv = 1.0f / lsum;
    const int q = qw + l16;
    u16* orow = Ab + ((size_t)(b * 2048 + q)) * 1024 + h * 64;
#pragma unroll
    for (int dn = 0; dn < 4; dn++) {
      us4 o = pk_bf16x4(f4{acc[dn][0] * rinv, acc[dn][1] * rinv,
                           acc[dn][2] * rinv, acc[dn][3] * rinv});
      *(us4*)(orow + dn * 16 + quad * 4) = o;
    }
  }
}

// ---------------- output projection + residual (64x128 tiles + T1 swizzle) ----------------
__global__ LB void gemm_out(const u16* __restrict__ Ab, const u16* __restrict__ Wob,
                            const float* __restrict__ X, float* __restrict__ Yp) {
  __shared__ u16 Als[64 * 32];
  __shared__ u16 Bls[128 * 32];
  const int tid = threadIdx.x;
  // T1: 512 blocks, 8 XCDs, 64/chunk (bijective). XCD k gets 8 consecutive
  // y-panels -> A rows stay in its private L2; Wob (2MB) L2-fits everywhere.
  const int wb = (blockIdx.x & 7) * 64 + (blockIdx.x >> 3);
  const int bx = wb & 7, by = wb >> 3;
  const int m0 = by * 64, n0 = bx * 128;
  const int w = tid >> 6, lane = tid & 63;
  const int l16 = lane & 15, quad = lane >> 4;
  f4 acc[4][2];
#pragma unroll
  for (int a = 0; a < 4; a++)
#pragma unroll
    for (int b = 0; b < 2; b++) acc[a][b] = f4{0.f, 0.f, 0.f, 0.f};

  for (int kk = 0; kk < 1024; kk += 32) {
    __syncthreads();
    {
      int cb = w * 64;
      int c = cb + lane;
      int row = c >> 2, kc = c & 3;
      GLDS(Ab + (size_t)(m0 + row) * 1024 + kk + kc * 8, &Als[cb * 8]);
    }
#pragma unroll
    for (int it = 0; it < 2; it++) {
      int cb = (w * 2 + it) * 64;
      int c = cb + lane;
      int row = c >> 2, kc = c & 3;
      GLDS(Wob + (size_t)(n0 + row) * 1024 + kk + kc * 8, &Bls[cb * 8]);
    }
    __syncthreads();
    bf8 af[4], bfr[2];
#pragma unroll
    for (int mt = 0; mt < 4; mt++)
      af[mt] = __builtin_bit_cast(bf8, *(const us8*)(&Als[(mt * 16 + l16) * 32 + quad * 8]));
#pragma unroll
    for (int nt = 0; nt < 2; nt++)
      bfr[nt] = __builtin_bit_cast(bf8, *(const us8*)(&Bls[(w * 32 + nt * 16 + l16) * 32 + quad * 8]));
#pragma unroll
    for (int mt = 0; mt < 4; mt++)
#pragma unroll
      for (int nt = 0; nt < 2; nt++)
        acc[mt][nt] = __builtin_amdgcn_mfma_f32_16x16x32_bf16(af[mt], bfr[nt], acc[mt][nt], 0, 0, 0);
  }

#pragma unroll
  for (int mt = 0; mt < 4; mt++)
#pragma unroll
    for (int nt = 0; nt < 2; nt++)
#pragma unroll
      for (int r = 0; r < 4; r++) {
        int m = m0 + mt * 16 + quad * 4 + r;
        int n = n0 + w * 32 + nt * 16 + l16;
        size_t o = (size_t)m * 1024 + n;
        Yp[o] = acc[mt][nt][r] + X[o];
      }
}

// ---------------- LayerNorm ----------------
__global__ LB void ln_kernel(const float* __restrict__ Y, const float* __restrict__ g,
                             const float* __restrict__ bta, float* __restrict__ out) {
  __shared__ float ls[4], lsq[4];
  const int row = blockIdx.x, tid = threadIdx.x;
  const int w = tid >> 6, lane = tid & 63;
  f4 v = *(const f4*)(Y + (size_t)row * 1024 + tid * 4);
  float s  = v[0] + v[1] + v[2] + v[3];
  float sq = v[0] * v[0] + v[1] * v[1] + v[2] * v[2] + v[3] * v[3];
#pragma unroll
  for (int d = 1; d < 64; d <<= 1) { s += __shfl_xor(s, d, 64); sq += __shfl_xor(sq, d, 64); }
  if (lane == 0) { ls[w] = s; lsq[w] = sq; }
  __syncthreads();
  s  = ls[0] + ls[1] + ls[2] + ls[3];
  sq = lsq[0] + lsq[1] + lsq[2] + lsq[3];
  float mu  = s * (1.0f / 1024.0f);
  float var = sq * (1.0f / 1024.0f) - mu * mu;
  float rs  = rsqrtf(var + 1e-5f);
  f4 o;
#pragma unroll
  for (int j = 0; j < 4; j++) {
    int col = tid * 4 + j;
    o[j] = (v[j] - mu) * rs * g[col] + bta[col];
  }
  *(f4*)(out + (size_t)row * 1024 + tid * 4) = o;
}

extern "C" void kernel_launch(void* const* d_in, const int* in_sizes, int n_in,
                              void* d_out, int out_size, void* d_ws, size_t ws_size,
                              hipStream_t stream) {
  (void)in_sizes; (void)n_in; (void)out_size; (void)ws_size;
  const float* X  = (const float*)d_in[0];
  const float* Wq = (const float*)d_in[1];
  const float* Wk = (const float*)d_in[2];
  const float* Wv = (const float*)d_in[3];
  const float* Wo = (const float*)d_in[4];
  const float* al = (const float*)d_in[5];
  const float* g  = (const float*)d_in[6];
  const float* bt = (const float*)d_in[7];

  char* ws = (char*)d_ws;
  float* Yp   = (float*)(ws);
  u16*   Xb   = (u16*)(ws + ((size_t)16 << 20));
  u16*   Wcat = (u16*)(ws + ((size_t)24 << 20));
  u16*   Wob  = (u16*)(ws + ((size_t)30 << 20));
  u16*   Qb   = (u16*)(ws + ((size_t)32 << 20));
  u16*   Kraw = (u16*)(ws + ((size_t)40 << 20));
  u16*   Ab   = (u16*)(ws + ((size_t)40 << 20));  // reuses Kraw
  u16*   Kp   = (u16*)(ws + ((size_t)48 << 20));
  u16*   Vp   = (u16*)(ws + ((size_t)56 << 20));

  cvt_kernel<<<dim3(4096), 256, 0, stream>>>(X, Wq, Wk, Wv, Wo, Xb, Wcat, Wob);
  gemm_qkv<<<dim3(768), 256, 0, stream>>>(Xb, Wcat, Qb, Kraw, Vp);
  ema_pe<<<dim3(2048), 256, 0, stream>>>(Kraw, al, Kp);
  attn_kernel<<<dim3(512), 256, 0, stream>>>(Qb, Kp, Vp, Ab);
  gemm_out<<<dim3(512), 256, 0, stream>>>(Ab, Wob, X, Yp);
  ln_kernel<<<dim3(4096), 256, 0, stream>>>(Yp, g, bt, (float*)d_out);
}

// Round 12
// 187.564 us; speedup vs baseline: 1.0605x; 1.0605x over previous
//
#include <hip/hip_runtime.h>

// Inputs/outputs fp32; internal compute bf16 MFMA (bf16-grade comparison).
// ws layout (64 MB):
//   [0,16M)   Yp    fp32 [B,S,D]
//   [16M,24M) Xb    bf16 [B*S, D]
//   [24M,30M) Wcat  bf16 [3072,1024]
//   [30M,32M) Wob   bf16 [1024,1024]
//   [32M,40M) Qb    bf16 [B,H,S,DK] (post-PE, pre-scaled by 0.125/ln2)
//   [40M,48M) Kraw  bf16 [B,H,S,DK] -> reused as Ab bf16 [B,S,D] after ema_pe
//   [48M,56M) Kp    bf16 packed K-frag order [bh][kt16][c][lane][j8]
//   [56M,64M) Vp    bf16 packed V^T-frag order [bh][kb64][t*4+dn][lane][j4]

#define LB __launch_bounds__(256)
// r6/r8/r15: NO min-waves hint / extra register footprint on attn.
// r10: NO loop-carried MFMA accumulator chains.
// R17/R18/R19 (counter-verified): epilogue register pressure is a first-class
// occupancy knob; serial cores live off cross-block TLP.
// R20 (94.5us): 8-phase 256^2 starves -- needs grid>=CUs and long K.
// R21 (57us): smaller qkv tiles regress -- serial core bound by staging-issue
// rate per MFMA; 128^2 is the local optimum.
// R24 (49us, VALU 40%, SGPR 112): counted-vmcnt 3-buf on the GEMM core costs
// more VALU than the drain it removes; serial+syncthreads certified for qkv.
// R25: attn -> one q-group per block, grid 1024 (4-5 blocks/CU, heavy-first
// g = 31-idx>>5); TLP is the only lever that worked every time (R18/R19).
// R26/R27: rounds 10-11 failed with NO timing dict at all -- failure at
// container ACQUISITION, before the kernel was staged/run. Kernel never
// executed; resubmitted UNCHANGED (audited: uniform barriers, bounded
// addresses, strict simplification of the 5x-benched R16 structure).

typedef unsigned short u16;
typedef unsigned int u32;
typedef __attribute__((ext_vector_type(2))) unsigned int u32x2;
typedef __attribute__((ext_vector_type(4))) unsigned short us4;
typedef __attribute__((ext_vector_type(8))) unsigned short us8;
typedef __attribute__((ext_vector_type(8))) __bf16 bf8;
typedef __attribute__((ext_vector_type(4))) float f4;
typedef __attribute__((ext_vector_type(4))) short s4;

// softmax scale folded into Q: exp(s/8) = exp2(s * 0.125/ln2)
#define QSCALE 0.18033688011112042f

#if __has_builtin(__builtin_amdgcn_exp2f)
#define EXP2 __builtin_amdgcn_exp2f   // raw v_exp_f32 (r14-validated: args never denormal)
#else
#define EXP2 exp2f
#endif

static __device__ __forceinline__ float bf2f(u16 h) {
  union { unsigned int u; float f; } c; c.u = ((unsigned int)h) << 16; return c.f;
}
static __device__ __forceinline__ u16 f2bf(float f) {
  union { float f; unsigned int u; } c; c.f = f;
  unsigned int u = c.u + 0x7FFFu + ((c.u >> 16) & 1u);
  return (u16)(u >> 16);
}
// pack 4 fp32 -> 4 bf16 (RNE); packed HW cvt when available
#if __has_builtin(__builtin_amdgcn_cvt_pk_bf16_f32)
typedef __attribute__((ext_vector_type(2))) __bf16 bf2v;
static __device__ __forceinline__ us4 pk_bf16x4(f4 v) {
  bf2v lo = __builtin_amdgcn_cvt_pk_bf16_f32(v[0], v[1]);
  bf2v hi = __builtin_amdgcn_cvt_pk_bf16_f32(v[2], v[3]);
  u32x2 r = {__builtin_bit_cast(u32, lo), __builtin_bit_cast(u32, hi)};
  return __builtin_bit_cast(us4, r);
}
#else
static __device__ __forceinline__ us4 pk_bf16x4(f4 v) {
  return us4{f2bf(v[0]), f2bf(v[1]), f2bf(v[2]), f2bf(v[3])};
}
#endif
static __device__ __forceinline__ float pe_val(int s, int dk) {
  float fr = __expf((float)(dk & ~1) * (-9.210340371976184f / 64.0f));
  float ang = (float)s * fr;
  return (dk & 1) ? __cosf(ang) : __sinf(ang);
}

// 16x16x16 bf16 MFMA, hedged across builtin generations (verified r5).
#if __has_builtin(__builtin_amdgcn_mfma_f32_16x16x16bf16_1k)
static __device__ __forceinline__ f4 mfma16(us4 a, us4 b, f4 c) {
  return __builtin_amdgcn_mfma_f32_16x16x16bf16_1k(
      __builtin_bit_cast(s4, a), __builtin_bit_cast(s4, b), c, 0, 0, 0);
}
#elif __has_builtin(__builtin_amdgcn_mfma_f32_16x16x16_bf16)
typedef __attribute__((ext_vector_type(4))) __bf16 bf4;
static __device__ __forceinline__ f4 mfma16(us4 a, us4 b, f4 c) {
  return __builtin_amdgcn_mfma_f32_16x16x16_bf16(
      __builtin_bit_cast(bf4, a), __builtin_bit_cast(bf4, b), c, 0, 0, 0);
}
#else
static __device__ __forceinline__ f4 mfma16(us4 a, us4 b, f4 c) {
  asm volatile("v_mfma_f32_16x16x16_bf16 %0, %1, %2, %0" : "+v"(c) : "v"(a), "v"(b));
  return c;
}
#endif

#define GLDS(gp, lp) __builtin_amdgcn_global_load_lds( \
    (const __attribute__((address_space(1))) void*)(gp), \
    (__attribute__((address_space(3))) void*)(lp), 16, 0, 0)

// ---------------- fp32 -> bf16 conversion pre-pass ----------------
__global__ LB void cvt_kernel(const float* __restrict__ X, const float* __restrict__ Wq,
                              const float* __restrict__ Wk, const float* __restrict__ Wv,
                              const float* __restrict__ Wo, u16* __restrict__ Xb,
                              u16* __restrict__ Wcat, u16* __restrict__ Wob) {
  const unsigned t = blockIdx.x * 256 + threadIdx.x;
  const float* src; u16* dst; size_t off;
  if (t < (512u << 10))      { src = X;  dst = Xb;                off = t; }
  else if (t < (640u << 10)) { src = Wq; dst = Wcat;              off = t - (512u << 10); }
  else if (t < (768u << 10)) { src = Wk; dst = Wcat + (1u << 20); off = t - (640u << 10); }
  else if (t < (896u << 10)) { src = Wv; dst = Wcat + (2u << 20); off = t - (768u << 10); }
  else                       { src = Wo; dst = Wob;               off = t - (896u << 10); }
  off *= 8;
  f4 a = *(const f4*)(src + off);
  f4 b = *(const f4*)(src + off + 4);
  us8 o = {f2bf(a[0]), f2bf(a[1]), f2bf(a[2]), f2bf(a[3]),
           f2bf(b[0]), f2bf(b[1]), f2bf(b[2]), f2bf(b[3])};
  *(us8*)(dst + off) = o;
}

// ---------------- m97-style serial GEMM core (R1/R19 known-good, FROZEN) ----------------
static __device__ __forceinline__ void gemm_core(
    const u16* __restrict__ Abase, const u16* __restrict__ Bbase,
    u16* Als, u16* Bls, int m0, int n0, int tid, f4 acc[4][4]) {
  const int w = tid >> 6, lane = tid & 63;
  const int l16 = lane & 15, quad = lane >> 4;
  const int wm = w & 1, wn = w >> 1;
  for (int kk = 0; kk < 1024; kk += 32) {
    __syncthreads();
#pragma unroll
    for (int it = 0; it < 2; it++) {
      int cb = (w * 2 + it) * 64;
      int c = cb + lane;
      int row = c >> 2, kc = c & 3;
      GLDS(Abase + (size_t)(m0 + row) * 1024 + kk + kc * 8, &Als[cb * 8]);
      GLDS(Bbase + (size_t)(n0 + row) * 1024 + kk + kc * 8, &Bls[cb * 8]);
    }
    __syncthreads();
    bf8 af[4], bfr[4];
#pragma unroll
    for (int mt = 0; mt < 4; mt++)
      af[mt] = __builtin_bit_cast(bf8, *(const us8*)(&Als[(wm * 64 + mt * 16 + l16) * 32 + quad * 8]));
#pragma unroll
    for (int nt = 0; nt < 4; nt++)
      bfr[nt] = __builtin_bit_cast(bf8, *(const us8*)(&Bls[(wn * 64 + nt * 16 + l16) * 32 + quad * 8]));
#pragma unroll
    for (int mt = 0; mt < 4; mt++)
#pragma unroll
      for (int nt = 0; nt < 4; nt++)
        acc[mt][nt] = __builtin_amdgcn_mfma_f32_16x16x32_bf16(af[mt], bfr[nt], acc[mt][nt], 0, 0, 0);
  }
}

// ---------------- QKV projection (fused N=3072), R23 config FROZEN ----------------
__global__ LB void gemm_qkv(const u16* __restrict__ Xb, const u16* __restrict__ Wcat,
                            u16* __restrict__ Qb, u16* __restrict__ Kraw,
                            u16* __restrict__ Vp) {
  __shared__ u16 Als[128 * 32];
  __shared__ u16 Bls[128 * 32];
  const int tid = threadIdx.x;
  // T1: 768 blocks, 8 XCDs, 96/chunk (bijective since 768%8==0).
  const int wb = (blockIdx.x & 7) * 96 + (blockIdx.x >> 3);
  const int bx = wb % 24, by = wb / 24;
  const int m0 = by * 128, n0 = bx * 128;
  f4 acc[4][4];
#pragma unroll
  for (int a = 0; a < 4; a++)
#pragma unroll
    for (int b = 0; b < 4; b++) acc[a][b] = f4{0.f, 0.f, 0.f, 0.f};
  gemm_core(Xb, Wcat, Als, Bls, m0, n0, tid, acc);

  const int w = tid >> 6, lane = tid & 63;
  const int l16 = lane & 15, quad = lane >> 4;
  const int wm = w & 1, wn = w >> 1;
  const int z = bx >> 3;  // 0:Q 1:K 2:V
#pragma unroll
  for (int mt = 0; mt < 4; mt++)
#pragma unroll
    for (int nt = 0; nt < 4; nt++)
#pragma unroll
      for (int r = 0; r < 4; r++) {
        int m = m0 + wm * 64 + mt * 16 + quad * 4 + r;
        int nn = (n0 + wn * 64 + nt * 16 + l16) & 1023;
        float v = acc[mt][nt][r];
        int b = m >> 11, s = m & 2047, h = nn >> 6, dk = nn & 63;
        size_t bhoff = (size_t)(b * 16 + h) * (2048 * 64);
        if (z == 0) {
          // pre-scale Q: scores exit QK^T already in exp2 domain
          Qb[bhoff + (size_t)s * 64 + dk] = f2bf((v + pe_val(s, dk)) * QSCALE);
        } else if (z == 1) {
          Kraw[bhoff + (size_t)s * 64 + dk] = f2bf(v);
        } else {
          // packed V^T-frag order: [kb64][(t*4+dn)][Q*16+l16 (=lane)][j]
          int kb = s >> 6, sl = s & 63;
          int t = sl >> 4, Qq = (sl >> 2) & 3, jj = sl & 3;
          int dn = dk >> 4, lv = dk & 15;
          Vp[bhoff + (size_t)kb * 4096 + ((t * 4 + dn) * 64 + Qq * 16 + lv) * 4 + jj] = f2bf(v);
        }
      }
}

// ---------------- EMA smear + PE on K; writes packed K-frag order ----------------
__global__ LB void ema_pe(const u16* __restrict__ Kraw, const float* __restrict__ alpha,
                          u16* __restrict__ Kp) {
  int idx = blockIdx.x * 256 + threadIdx.x;
  int b8  = idx & 7;
  int s   = (idx >> 3) & 2047;
  int bh  = idx >> 14;
  int dk8 = b8 * 8;
  size_t base = ((size_t)bh * 2048 + s) * 64 + dk8;
  us8 kc = *(const us8*)(Kraw + base);
  float kv[8];
#pragma unroll
  for (int j = 0; j < 8; j++) kv[j] = bf2f(kc[j]);
  if (s > 0) {
    us8 kp = *(const us8*)(Kraw + base - 64);
    float aa = alpha[(bh & 15) * 2047 + s - 1];
    float a = 1.0f / (1.0f + __expf(-aa));
#pragma unroll
    for (int j = 0; j < 8; j++) kv[j] = kv[j] * a + bf2f(kp[j]) * (1.0f - a);
  }
  us8 o;
#pragma unroll
  for (int j = 0; j < 8; j++) o[j] = f2bf(kv[j] + pe_val(s, dk8 + j));
  int kt16 = s >> 4, c = b8 >> 2, quad = b8 & 3, l16s = s & 15;
  size_t off = (size_t)bh * (2048 * 64) + (size_t)kt16 * 1024 + (c * 64 + quad * 16 + l16s) * 8;
  *(us8*)(Kp + off) = o;
}

// ---------------- causal attention: one q-group per block, grid 1024 ----------------
// Block = 4 waves x 16 q-rows = 64 q-rows sharing one staged K/V stream.
// Heavy-first: g = 31 - idx>>5, so T=32 blocks dispatch first; 4-5 blocks/CU
// co-residency does the load balancing (R25 -- TLP is the proven lever).
// p = exp2(s) with Q pre-scaled (uniform factor cancels in O = sum(pv)/sum(p)).
template<bool MASK>
static __device__ __forceinline__ void attn_step_lds(
    const u16* kbase, const u16* vbase,
    const bf8* qf, f4* acc, float& lsum, int lane, int quad, int qrel0) {
  f4 sc[4];
#pragma unroll
  for (int t = 0; t < 4; t++) sc[t] = f4{0.f, 0.f, 0.f, 0.f};
#pragma unroll
  for (int t = 0; t < 4; t++)
#pragma unroll
    for (int c = 0; c < 2; c++) {
      bf8 kf = __builtin_bit_cast(bf8, *(const us8*)(kbase + (t * 2 + c) * 512 + lane * 8));
      sc[t] = __builtin_amdgcn_mfma_f32_16x16x32_bf16(kf, qf[c], sc[t], 0, 0, 0);
    }
  us4 pf[4];
#pragma unroll
  for (int t = 0; t < 4; t++) {
    f4 pv;
#pragma unroll
    for (int r = 0; r < 4; r++) {
      float s = sc[t][r];
      if (MASK && (t * 16 + quad * 4 + r > qrel0)) s = -1e30f;
      float p = EXP2(s);          // raw v_exp_f32
      lsum += p;
      pv[r] = p;
    }
    pf[t] = pk_bf16x4(pv);
  }
#pragma unroll
  for (int t = 0; t < 4; t++)
#pragma unroll
    for (int dn = 0; dn < 4; dn++) {
      us4 vf = *(const us4*)(vbase + ((t * 4 + dn) * 64 + lane) * 4);
      acc[dn] = mfma16(vf, pf[t], acc[dn]);
    }
}

__global__ LB void attn_kernel(const u16* __restrict__ Qb, const u16* __restrict__ Kp,
                               const u16* __restrict__ Vp, u16* __restrict__ Ab) {
  __shared__ u16 Kls[2][4096];   // double-buffered 64-key K tile (packed frag order)
  __shared__ u16 Vls[2][4096];   // double-buffered 64-key V^T tile
  const int tid = threadIdx.x, w = tid >> 6, lane = tid & 63;
  const int l16 = lane & 15, quad = lane >> 4;
  const int idx = blockIdx.x;
  const int bh = idx & 31;        // XCD locality: each XCD's blocks touch only 4 heads
  const int g  = 31 - (idx >> 5); // heavy-first q-group (64 rows)
  const size_t bhoff = (size_t)bh * (2048 * 64);
  const u16* Kt = Kp + bhoff;
  const u16* Vt = Vp + bhoff;
  const int b = bh >> 4, h = bh & 15;
  const int T  = g + 1;            // 64-key steps (last one masked)
  const int qw = g * 64 + w * 16;  // this wave's 16 q-rows

  bf8 qf[2];
#pragma unroll
  for (int c = 0; c < 2; c++)
    qf[c] = __builtin_bit_cast(bf8, *(const us8*)(Qb + bhoff + (size_t)(qw + l16) * 64 + c * 32 + quad * 8));

  f4 acc[4];
#pragma unroll
  for (int dn = 0; dn < 4; dn++) acc[dn] = f4{0.f, 0.f, 0.f, 0.f};
  float lsum = 0.f;

  // prologue: stage kb=0 into buffer 0 (each wave: 2KB of K + 2KB of V, linear)
  {
    const u16* kg = Kt + w * 1024;
    const u16* vg = Vt + w * 1024;
    GLDS(kg + lane * 8,       &Kls[0][w * 1024]);
    GLDS(kg + 512 + lane * 8, &Kls[0][w * 1024 + 512]);
    GLDS(vg + lane * 8,       &Vls[0][w * 1024]);
    GLDS(vg + 512 + lane * 8, &Vls[0][w * 1024 + 512]);
  }
  asm volatile("s_waitcnt vmcnt(0)" ::: "memory");
  __builtin_amdgcn_s_barrier();

  for (int kb = 0; kb < T; kb++) {
    const int cur = kb & 1;
    if (kb + 1 < T) {   // prefetch next tile into the other buffer (overlaps compute)
      const u16* kg = Kt + (size_t)(kb + 1) * 4096 + w * 1024;
      const u16* vg = Vt + (size_t)(kb + 1) * 4096 + w * 1024;
      u16* kl = &Kls[cur ^ 1][w * 1024];
      u16* vl = &Vls[cur ^ 1][w * 1024];
      GLDS(kg + lane * 8, kl);
      GLDS(kg + 512 + lane * 8, kl + 512);
      GLDS(vg + lane * 8, vl);
      GLDS(vg + 512 + lane * 8, vl + 512);
    }
    if (kb == T - 1)
      attn_step_lds<true>(&Kls[cur][0], &Vls[cur][0], qf, acc, lsum, lane, quad, w * 16 + l16);
    else
      attn_step_lds<false>(&Kls[cur][0], &Vls[cur][0], qf, acc, lsum, lane, quad, 0);
    asm volatile("s_waitcnt vmcnt(0)" ::: "memory");  // prefetch landed (had full compute to hide)
    __builtin_amdgcn_s_barrier();                     // all waves done reading buf[cur]
  }

  // epilogue: per-wave softmax denominator (reduce over quads) + store
  lsum += __shfl_xor(lsum, 16, 64);
  lsum += __shfl_xor(lsum, 32, 64);
  float rinv = 1.0f / lsum;
  const int q = qw + l16;
  u16* orow = Ab + ((size_t)(b * 2048 + q)) * 1024 + h * 64;
#pragma unroll
  for (int dn = 0; dn < 4; dn++) {
    us4 o = pk_bf16x4(f4{acc[dn][0] * rinv, acc[dn][1] * rinv,
                         acc[dn][2] * rinv, acc[dn][3] * rinv});
    *(us4*)(orow + dn * 16 + quad * 4) = o;
  }
}

// ---------------- output projection + residual (64x128 tiles + T1 swizzle) ----------------
__global__ LB void gemm_out(const u16* __restrict__ Ab, const u16* __restrict__ Wob,
                            const float* __restrict__ X, float* __restrict__ Yp) {
  __shared__ u16 Als[64 * 32];
  __shared__ u16 Bls[128 * 32];
  const int tid = threadIdx.x;
  // T1: 512 blocks, 8 XCDs, 64/chunk (bijective). XCD k gets 8 consecutive
  // y-panels -> A rows stay in its private L2; Wob (2MB) L2-fits everywhere.
  const int wb = (blockIdx.x & 7) * 64 + (blockIdx.x >> 3);
  const int bx = wb & 7, by = wb >> 3;
  const int m0 = by * 64, n0 = bx * 128;
  const int w = tid >> 6, lane = tid & 63;
  const int l16 = lane & 15, quad = lane >> 4;
  f4 acc[4][2];
#pragma unroll
  for (int a = 0; a < 4; a++)
#pragma unroll
    for (int b = 0; b < 2; b++) acc[a][b] = f4{0.f, 0.f, 0.f, 0.f};

  for (int kk = 0; kk < 1024; kk += 32) {
    __syncthreads();
    {
      int cb = w * 64;
      int c = cb + lane;
      int row = c >> 2, kc = c & 3;
      GLDS(Ab + (size_t)(m0 + row) * 1024 + kk + kc * 8, &Als[cb * 8]);
    }
#pragma unroll
    for (int it = 0; it < 2; it++) {
      int cb = (w * 2 + it) * 64;
      int c = cb + lane;
      int row = c >> 2, kc = c & 3;
      GLDS(Wob + (size_t)(n0 + row) * 1024 + kk + kc * 8, &Bls[cb * 8]);
    }
    __syncthreads();
    bf8 af[4], bfr[2];
#pragma unroll
    for (int mt = 0; mt < 4; mt++)
      af[mt] = __builtin_bit_cast(bf8, *(const us8*)(&Als[(mt * 16 + l16) * 32 + quad * 8]));
#pragma unroll
    for (int nt = 0; nt < 2; nt++)
      bfr[nt] = __builtin_bit_cast(bf8, *(const us8*)(&Bls[(w * 32 + nt * 16 + l16) * 32 + quad * 8]));
#pragma unroll
    for (int mt = 0; mt < 4; mt++)
#pragma unroll
      for (int nt = 0; nt < 2; nt++)
        acc[mt][nt] = __builtin_amdgcn_mfma_f32_16x16x32_bf16(af[mt], bfr[nt], acc[mt][nt], 0, 0, 0);
  }

#pragma unroll
  for (int mt = 0; mt < 4; mt++)
#pragma unroll
    for (int nt = 0; nt < 2; nt++)
#pragma unroll
      for (int r = 0; r < 4; r++) {
        int m = m0 + mt * 16 + quad * 4 + r;
        int n = n0 + w * 32 + nt * 16 + l16;
        size_t o = (size_t)m * 1024 + n;
        Yp[o] = acc[mt][nt][r] + X[o];
      }
}

// ---------------- LayerNorm ----------------
__global__ LB void ln_kernel(const float* __restrict__ Y, const float* __restrict__ g,
                             const float* __restrict__ bta, float* __restrict__ out) {
  __shared__ float ls[4], lsq[4];
  const int row = blockIdx.x, tid = threadIdx.x;
  const int w = tid >> 6, lane = tid & 63;
  f4 v = *(const f4*)(Y + (size_t)row * 1024 + tid * 4);
  float s  = v[0] + v[1] + v[2] + v[3];
  float sq = v[0] * v[0] + v[1] * v[1] + v[2] * v[2] + v[3] * v[3];
#pragma unroll
  for (int d = 1; d < 64; d <<= 1) { s += __shfl_xor(s, d, 64); sq += __shfl_xor(sq, d, 64); }
  if (lane == 0) { ls[w] = s; lsq[w] = sq; }
  __syncthreads();
  s  = ls[0] + ls[1] + ls[2] + ls[3];
  sq = lsq[0] + lsq[1] + lsq[2] + lsq[3];
  float mu  = s * (1.0f / 1024.0f);
  float var = sq * (1.0f / 1024.0f) - mu * mu;
  float rs  = rsqrtf(var + 1e-5f);
  f4 o;
#pragma unroll
  for (int j = 0; j < 4; j++) {
    int col = tid * 4 + j;
    o[j] = (v[j] - mu) * rs * g[col] + bta[col];
  }
  *(f4*)(out + (size_t)row * 1024 + tid * 4) = o;
}

extern "C" void kernel_launch(void* const* d_in, const int* in_sizes, int n_in,
                              void* d_out, int out_size, void* d_ws, size_t ws_size,
                              hipStream_t stream) {
  (void)in_sizes; (void)n_in; (void)out_size; (void)ws_size;
  const float* X  = (const float*)d_in[0];
  const float* Wq = (const float*)d_in[1];
  const float* Wk = (const float*)d_in[2];
  const float* Wv = (const float*)d_in[3];
  const float* Wo = (const float*)d_in[4];
  const float* al = (const float*)d_in[5];
  const float* g  = (const float*)d_in[6];
  const float* bt = (const float*)d_in[7];

  char* ws = (char*)d_ws;
  float* Yp   = (float*)(ws);
  u16*   Xb   = (u16*)(ws + ((size_t)16 << 20));
  u16*   Wcat = (u16*)(ws + ((size_t)24 << 20));
  u16*   Wob  = (u16*)(ws + ((size_t)30 << 20));
  u16*   Qb   = (u16*)(ws + ((size_t)32 << 20));
  u16*   Kraw = (u16*)(ws + ((size_t)40 << 20));
  u16*   Ab   = (u16*)(ws + ((size_t)40 << 20));  // reuses Kraw
  u16*   Kp   = (u16*)(ws + ((size_t)48 << 20));
  u16*   Vp   = (u16*)(ws + ((size_t)56 << 20));

  cvt_kernel<<<dim3(4096), 256, 0, stream>>>(X, Wq, Wk, Wv, Wo, Xb, Wcat, Wob);
  gemm_qkv<<<dim3(768), 256, 0, stream>>>(Xb, Wcat, Qb, Kraw, Vp);
  ema_pe<<<dim3(2048), 256, 0, stream>>>(Kraw, al, Kp);
  attn_kernel<<<dim3(1024), 256, 0, stream>>>(Qb, Kp, Vp, Ab);
  gemm_out<<<dim3(512), 256, 0, stream>>>(Ab, Wob, X, Yp);
  ln_kernel<<<dim3(4096), 256, 0, stream>>>(Yp, g, bt, (float*)d_out);
}